// Round 8
// baseline (97.585 us; speedup 1.0000x reference)
//
#include <hip/hip_runtime.h>

// PrRoIPool2D forward, MI355X. B=8, C=256, H=W=48, R=300, 7x7 bins, scale=1/16.
// R18: NO LDS patch — PA reads feature taps DIRECTLY from global (L1/L2).
//  - R17 audit: patch was a pure pass-through (written once, read ~1.1x) that
//    added write+fence+read to the dependent chain and pinned LDS at 25.9KB
//    (24 waves/CU cap) + 24 staging VGPRs (~70 total -> possible 16-wave cap).
//  - now: LDS = rs only (5.2 KB/block); launch_bounds(256,8) targets <=64
//    VGPR -> 32 waves/CU (max). Chain: roi -> bounds -> 12 tap-loads
//    (all issued up front, L1/L2-shared across pw-lanes and ROIs) -> FMA ->
//    rs -> fence -> PB. One fence, one LDS round trip (tiny rs), no staging.
//  - wave = (r, channel-pair), 9600 independent waves (best-measured
//    structure, R14); grid dim3(32,300) keeps channel->XCD partition.
//  - tap loads are float4+float2 at column 'base' (dword-aligned, in-bounds:
//    I0 <= base <= I0+4*NI4-6 <= FW-6; rows J0..J0+JROWS-1 <= FH-1).
// Numerics: identical values, identical FMA order (wx0..wx5 then wy0..wy5,
// then *inv_area) as R10-R17 -> bit-identical outputs, absmax unchanged.

#define PH 7
#define PW 7
#define NBINS 49
#define SCALE 0.0625f
#define CH 256
#define FH 48
#define FW 48
#define RNUM 300
#define RSF 328                  // 7*23*2 = 322, padded

__device__ __forceinline__ float hat_int(float x, float g) {
    float t = x - (g - 1.0f);
    if (t <= 0.0f) return 0.0f;
    if (t <= 1.0f) return 0.5f * t * t;
    if (t <= 2.0f) { float u = 2.0f - t; return 1.0f - 0.5f * u * u; }
    return 1.0f;
}

__global__ __launch_bounds__(256, 8)
void prroi_direct(const float* __restrict__ feat,
                  const float* __restrict__ rois,
                  float* __restrict__ out) {
    const int wv   = threadIdx.x >> 6;          // wave 0..3
    const int lane = threadIdx.x & 63;
    const int r    = blockIdx.y;                // 0..299
    const int cpr  = blockIdx.x * 4 + wv;       // channel pair 0..127
    const int c0   = cpr * 2;

    __shared__ float rs[4][RSF];                // per-wave row-sums, 5248 B
    float* rsw = rs[wv];

    // ---- trip 1: roi row (wave-uniform -> scalar loads) ----
    const float* roi = rois + r * 5;
    const float f0 = roi[0], f1 = roi[1], f2 = roi[2], f3 = roi[3], f4 = roi[4];
    const int   b  = (int)f0;
    const float x1 = f1 * SCALE, y1 = f2 * SCALE;
    const float x2 = f3 * SCALE, y2 = f4 * SCALE;
    const float roi_w = fmaxf(x2 - x1, 0.0f), roi_h = fmaxf(y2 - y1, 0.0f);
    const float bin_w = roi_w / (float)PW, bin_h = roi_h / (float)PH;
    const float area = bin_w * bin_h;
    const float ia   = (area > 0.0f) ? (1.0f / area) : 0.0f;

    const float ylo = fminf(y1, y2), yhi = fmaxf(y1, y2);
    const float xlo = fminf(x1, x2), xhi = fmaxf(x1, x2);
    const int j1 = min(FH - 1, (int)floorf(yhi) + 1);
    const int i1 = min(FW - 1, (int)floorf(xhi) + 1);
    const int J0 = min(max(0, (int)floorf(ylo) - 1), FH - 6);
    const int I0 = min(max(0, (int)floorf(xlo) - 1) & ~3, FW - 8);
    const int JROWS = min(FH - J0, max(j1 - J0 + 1, 6));        // 6..23
    int NI4 = min(((i1 - I0) >> 2) + 1, (FW - I0) >> 2);
    NI4 = max(NI4, 2);                                           // 2..7

    // ---- PA role + tap base (needed for load addresses) ----
    const int  pwA = lane >> 3, jsl = lane & 7;
    const bool actA = lane < 56;
    int base = I0;
    float xa = 0.0f, xb = 0.0f;
    if (actA) {
        xa = x1 + pwA * bin_w; xb = xa + bin_w;
        base = min(max((int)floorf(xa) - 1, I0), I0 + 4 * NI4 - 6);
    }

    // ---- trip 2: issue ALL tap loads now (3 rows x 2 ch, f4+f2 each) ----
    const float* fb = feat + (size_t)(b * CH + c0) * (FH * FW);
    const bool m0 = actA && (jsl      < JROWS);
    const bool m1 = actA && (jsl + 8  < JROWS);
    const bool m2 = actA && (jsl + 16 < JROWS);
    const float* p0 = fb + (size_t)(J0 + jsl) * FW + base;
    float4 a40, b40, a41, b41, a42, b42;
    float2 a20, b20, a21, b21, a22, b22;
    if (m0) {
        a40 = *(const float4*)(p0);            a20 = *(const float2*)(p0 + 4);
        b40 = *(const float4*)(p0 + FH * FW);  b20 = *(const float2*)(p0 + FH * FW + 4);
    }
    if (m1) {
        const float* p1 = p0 + 8 * FW;
        a41 = *(const float4*)(p1);            a21 = *(const float2*)(p1 + 4);
        b41 = *(const float4*)(p1 + FH * FW);  b21 = *(const float2*)(p1 + FH * FW + 4);
    }
    if (m2) {
        const float* p2 = p0 + 16 * FW;
        a42 = *(const float4*)(p2);            a22 = *(const float2*)(p2 + 4);
        b42 = *(const float4*)(p2 + FH * FW);  b22 = *(const float2*)(p2 + FH * FW + 4);
    }

    // ---- weights in registers, computed UNDER the load shadow ----
    float wx0 = 0, wx1 = 0, wx2 = 0, wx3 = 0, wx4 = 0, wx5 = 0;
    if (actA) {
        wx0 = hat_int(xb, (float)(base + 0)) - hat_int(xa, (float)(base + 0));
        wx1 = hat_int(xb, (float)(base + 1)) - hat_int(xa, (float)(base + 1));
        wx2 = hat_int(xb, (float)(base + 2)) - hat_int(xa, (float)(base + 2));
        wx3 = hat_int(xb, (float)(base + 3)) - hat_int(xa, (float)(base + 3));
        wx4 = hat_int(xb, (float)(base + 4)) - hat_int(xa, (float)(base + 4));
        wx5 = hat_int(xb, (float)(base + 5)) - hat_int(xa, (float)(base + 5));
    }
    const bool actB = lane < NBINS;
    float wy0 = 0, wy1 = 0, wy2 = 0, wy3 = 0, wy4 = 0, wy5 = 0;
    int pwB = 0, bjB = 0;
    if (actB) {
        const int ph = lane / 7;
        pwB = lane - ph * 7;
        const float ya = y1 + ph * bin_h, yb = ya + bin_h;
        const int bs = min(max((int)floorf(ya) - 1, J0), J0 + JROWS - 6);
        bjB = bs - J0;
        wy0 = hat_int(yb, (float)(bs + 0)) - hat_int(ya, (float)(bs + 0));
        wy1 = hat_int(yb, (float)(bs + 1)) - hat_int(ya, (float)(bs + 1));
        wy2 = hat_int(yb, (float)(bs + 2)) - hat_int(ya, (float)(bs + 2));
        wy3 = hat_int(yb, (float)(bs + 3)) - hat_int(ya, (float)(bs + 3));
        wy4 = hat_int(yb, (float)(bs + 4)) - hat_int(ya, (float)(bs + 4));
        wy5 = hat_int(yb, (float)(bs + 5)) - hat_int(ya, (float)(bs + 5));
    }

    // ---- PA: rs[pw][jr][c2] = sum_i wx * taps (vmcnt waits land here) ----
    if (m0) {
        float ax = 0.0f, ay = 0.0f;
        ax += wx0 * a40.x; ay += wx0 * b40.x;
        ax += wx1 * a40.y; ay += wx1 * b40.y;
        ax += wx2 * a40.z; ay += wx2 * b40.z;
        ax += wx3 * a40.w; ay += wx3 * b40.w;
        ax += wx4 * a20.x; ay += wx4 * b20.x;
        ax += wx5 * a20.y; ay += wx5 * b20.y;
        *(float2*)&rsw[(pwA * 23 + jsl) * 2] = make_float2(ax, ay);
    }
    if (m1) {
        float ax = 0.0f, ay = 0.0f;
        ax += wx0 * a41.x; ay += wx0 * b41.x;
        ax += wx1 * a41.y; ay += wx1 * b41.y;
        ax += wx2 * a41.z; ay += wx2 * b41.z;
        ax += wx3 * a41.w; ay += wx3 * b41.w;
        ax += wx4 * a21.x; ay += wx4 * b21.x;
        ax += wx5 * a21.y; ay += wx5 * b21.y;
        *(float2*)&rsw[(pwA * 23 + jsl + 8) * 2] = make_float2(ax, ay);
    }
    if (m2) {
        float ax = 0.0f, ay = 0.0f;
        ax += wx0 * a42.x; ay += wx0 * b42.x;
        ax += wx1 * a42.y; ay += wx1 * b42.y;
        ax += wx2 * a42.z; ay += wx2 * b42.z;
        ax += wx3 * a42.w; ay += wx3 * b42.w;
        ax += wx4 * a22.x; ay += wx4 * b22.x;
        ax += wx5 * a22.y; ay += wx5 * b22.y;
        *(float2*)&rsw[(pwA * 23 + jsl + 16) * 2] = make_float2(ax, ay);
    }
    asm volatile("s_waitcnt lgkmcnt(0)" ::: "memory");

    // ---- PB: out[bin][c2] = sum_j wy * rs ----
    if (actB) {
        const float* rb = rsw + (pwB * 23 + bjB) * 2;
        const float2 u0 = *(const float2*)(rb + 0);
        const float2 u1 = *(const float2*)(rb + 2);
        const float2 u2 = *(const float2*)(rb + 4);
        const float2 u3 = *(const float2*)(rb + 6);
        const float2 u4 = *(const float2*)(rb + 8);
        const float2 u5 = *(const float2*)(rb + 10);
        float ax = 0.0f, ay = 0.0f;
        ax += wy0 * u0.x; ay += wy0 * u0.y;
        ax += wy1 * u1.x; ay += wy1 * u1.y;
        ax += wy2 * u2.x; ay += wy2 * u2.y;
        ax += wy3 * u3.x; ay += wy3 * u3.y;
        ax += wy4 * u4.x; ay += wy4 * u4.y;
        ax += wy5 * u5.x; ay += wy5 * u5.y;
        float* o = out + ((size_t)r * CH + c0) * NBINS + lane;
        o[0]     = ax * ia;                     // channel c0
        o[NBINS] = ay * ia;                     // channel c0+1
    }
}

extern "C" void kernel_launch(void* const* d_in, const int* in_sizes, int n_in,
                              void* d_out, int out_size, void* d_ws, size_t ws_size,
                              hipStream_t stream) {
    const float* feat = (const float*)d_in[0];
    const float* rois = (const float*)d_in[1];
    float* out = (float*)d_out;
    (void)d_ws; (void)ws_size;

    prroi_direct<<<dim3(32, RNUM), 256, 0, stream>>>(feat, rois, out);
}

// Round 9
// 89.198 us; speedup vs baseline: 1.0940x; 1.0940x over previous
//
#include <hip/hip_runtime.h>

// PrRoIPool2D forward, MI355X. B=8, C=256, H=W=48, R=300, 7x7 bins, scale=1/16.
// R19: wave = (r, 4 channels) — amortize fixed per-wave cost 2x.
//  - R18 post-mortem: kernel is request+issue bound; best cluster's per-wave
//    VALU (~450 for 2ch: ~250 fixed bounds/weights + ~200 work) is the
//    largest pipe term (~14us chip-wide). Pay the fixed 250 once per 4
//    channels: interleaved patch [j][i][c4], float4 accumulators, b128 LDS
//    taps. Per-channel VALU 225 -> ~105 (2.1x). Waves 38400 -> 19200.
//  - coalesced staging kept (R18: scatter regresses); barrier-free wave-
//    private structure kept (R13/R15: lockstep/long chains regress).
//  - LDS 12.9 KB/wave -> 3 blocks/CU = 12 waves/CU (down from 24; barrier-
//    free + 2-trip chain should still cover latency).
//  - grid dim3(16,300); launch_bounds(256,3).
// Numerics: per-channel accumulation order identical to R10-R18 (x-taps
// ii=0..5 -> rs -> y-taps jj=0..5 -> *inv_area) -> bit-identical outputs.

#define PH 7
#define PW 7
#define NBINS 49
#define SCALE 0.0625f
#define CH 256
#define FH 48
#define FW 48
#define RNUM 300
#define PATCHF (23 * 28 * 4)     // [j<23][i<28][c4] linear, 10304 B
#define RSF 648                  // 7*23*4 = 644, padded

__device__ __forceinline__ float hat_int(float x, float g) {
    float t = x - (g - 1.0f);
    if (t <= 0.0f) return 0.0f;
    if (t <= 1.0f) return 0.5f * t * t;
    if (t <= 2.0f) { float u = 2.0f - t; return 1.0f - 0.5f * u * u; }
    return 1.0f;
}

__global__ __launch_bounds__(256, 3)
void prroi_c4(const float* __restrict__ feat,
              const float* __restrict__ rois,
              float* __restrict__ out) {
    const int wv   = threadIdx.x >> 6;          // wave 0..3
    const int lane = threadIdx.x & 63;
    const int r    = blockIdx.y;                // 0..299
    const int cq   = blockIdx.x * 4 + wv;       // channel quad 0..63
    const int c0   = cq * 4;

    __shared__ float lds[4][PATCHF + RSF];      // 51584 B -> 3 blocks/CU
    float* patch = lds[wv];
    float* rsw   = lds[wv] + PATCHF;

    // ---- trip 1: roi row (wave-uniform -> scalar loads) ----
    const float* roi = rois + r * 5;
    const float f0 = roi[0], f1 = roi[1], f2 = roi[2], f3 = roi[3], f4 = roi[4];
    const int   b  = (int)f0;
    const float x1 = f1 * SCALE, y1 = f2 * SCALE;
    const float x2 = f3 * SCALE, y2 = f4 * SCALE;
    const float roi_w = fmaxf(x2 - x1, 0.0f), roi_h = fmaxf(y2 - y1, 0.0f);
    const float bin_w = roi_w / (float)PW, bin_h = roi_h / (float)PH;
    const float area = bin_w * bin_h;
    const float ia   = (area > 0.0f) ? (1.0f / area) : 0.0f;

    const float ylo = fminf(y1, y2), yhi = fmaxf(y1, y2);
    const float xlo = fminf(x1, x2), xhi = fmaxf(x1, x2);
    const int j1 = min(FH - 1, (int)floorf(yhi) + 1);
    const int i1 = min(FW - 1, (int)floorf(xhi) + 1);
    const int J0 = min(max(0, (int)floorf(ylo) - 1), FH - 6);
    const int I0 = min(max(0, (int)floorf(xlo) - 1) & ~3, FW - 8);
    const int JROWS = min(FH - J0, max(j1 - J0 + 1, 6));        // 6..23
    int NI4 = min(((i1 - I0) >> 2) + 1, (FW - I0) >> 2);
    NI4 = max(NI4, 2);                                           // 2..7

    // ---- trip 2: issue ALL feature loads (4 channel planes, coalesced) ----
    const int NU = JROWS << 3;                  // (j, i4) units, i4 in 0..7
    const float* fb = feat + (size_t)(b * CH + c0) * (FH * FW);
    bool act_[3]; int dst_[3];
    float4 pc[3][4];
#pragma unroll
    for (int s = 0; s < 3; ++s) {
        const int u  = lane + (s << 6);
        const int j  = u >> 3, i4 = u & 7;
        const bool a = (u < NU) && (i4 < NI4);
        act_[s] = a;
        dst_[s] = (j * 28 + 4 * i4) * 4;
        if (a) {
            const float* src = fb + (size_t)(J0 + j) * FW + I0 + 4 * i4;
            pc[s][0] = *(const float4*)(src);                // channel c0
            pc[s][1] = *(const float4*)(src + FH * FW);      // c0+1
            pc[s][2] = *(const float4*)(src + 2 * FH * FW);  // c0+2
            pc[s][3] = *(const float4*)(src + 3 * FH * FW);  // c0+3
        }
    }

    // ---- weights in registers, computed UNDER the load shadow ----
    const int  pwA = lane >> 3, jsl = lane & 7;
    const bool actA = lane < 56;
    float wx0 = 0, wx1 = 0, wx2 = 0, wx3 = 0, wx4 = 0, wx5 = 0;
    int biA = 0;
    if (actA) {
        const float xa = x1 + pwA * bin_w, xb = xa + bin_w;
        const int base = min(max((int)floorf(xa) - 1, I0), I0 + 4 * NI4 - 6);
        biA = base - I0;
        wx0 = hat_int(xb, (float)(base + 0)) - hat_int(xa, (float)(base + 0));
        wx1 = hat_int(xb, (float)(base + 1)) - hat_int(xa, (float)(base + 1));
        wx2 = hat_int(xb, (float)(base + 2)) - hat_int(xa, (float)(base + 2));
        wx3 = hat_int(xb, (float)(base + 3)) - hat_int(xa, (float)(base + 3));
        wx4 = hat_int(xb, (float)(base + 4)) - hat_int(xa, (float)(base + 4));
        wx5 = hat_int(xb, (float)(base + 5)) - hat_int(xa, (float)(base + 5));
    }
    const bool actB = lane < NBINS;
    float wy0 = 0, wy1 = 0, wy2 = 0, wy3 = 0, wy4 = 0, wy5 = 0;
    int pwB = 0, bjB = 0;
    if (actB) {
        const int ph = lane / 7;
        pwB = lane - ph * 7;
        const float ya = y1 + ph * bin_h, yb = ya + bin_h;
        const int bs = min(max((int)floorf(ya) - 1, J0), J0 + JROWS - 6);
        bjB = bs - J0;
        wy0 = hat_int(yb, (float)(bs + 0)) - hat_int(ya, (float)(bs + 0));
        wy1 = hat_int(yb, (float)(bs + 1)) - hat_int(ya, (float)(bs + 1));
        wy2 = hat_int(yb, (float)(bs + 2)) - hat_int(ya, (float)(bs + 2));
        wy3 = hat_int(yb, (float)(bs + 3)) - hat_int(ya, (float)(bs + 3));
        wy4 = hat_int(yb, (float)(bs + 4)) - hat_int(ya, (float)(bs + 4));
        wy5 = hat_int(yb, (float)(bs + 5)) - hat_int(ya, (float)(bs + 5));
    }

    // ---- stage patch [j][i][c4] (4x4 register transpose, b128 writes) ----
#pragma unroll
    for (int s = 0; s < 3; ++s) {
        if (act_[s]) {
            float* d = patch + dst_[s];
            *(float4*)(d +  0) = make_float4(pc[s][0].x, pc[s][1].x, pc[s][2].x, pc[s][3].x);
            *(float4*)(d +  4) = make_float4(pc[s][0].y, pc[s][1].y, pc[s][2].y, pc[s][3].y);
            *(float4*)(d +  8) = make_float4(pc[s][0].z, pc[s][1].z, pc[s][2].z, pc[s][3].z);
            *(float4*)(d + 12) = make_float4(pc[s][0].w, pc[s][1].w, pc[s][2].w, pc[s][3].w);
        }
    }
    asm volatile("s_waitcnt lgkmcnt(0)" ::: "memory");

    // ---- PA: rs[pw][jr][c4] = sum_i wx * patch (b128 taps, 4ch FMA) ----
    if (actA) {
        for (int jr = jsl; jr < JROWS; jr += 8) {
            const float* row = patch + (jr * 28 + biA) * 4;
            const float4 v0 = *(const float4*)(row +  0);
            const float4 v1 = *(const float4*)(row +  4);
            const float4 v2 = *(const float4*)(row +  8);
            const float4 v3 = *(const float4*)(row + 12);
            const float4 v4 = *(const float4*)(row + 16);
            const float4 v5 = *(const float4*)(row + 20);
            float ax = 0.0f, ay = 0.0f, az = 0.0f, aw = 0.0f;
            ax += wx0 * v0.x; ay += wx0 * v0.y; az += wx0 * v0.z; aw += wx0 * v0.w;
            ax += wx1 * v1.x; ay += wx1 * v1.y; az += wx1 * v1.z; aw += wx1 * v1.w;
            ax += wx2 * v2.x; ay += wx2 * v2.y; az += wx2 * v2.z; aw += wx2 * v2.w;
            ax += wx3 * v3.x; ay += wx3 * v3.y; az += wx3 * v3.z; aw += wx3 * v3.w;
            ax += wx4 * v4.x; ay += wx4 * v4.y; az += wx4 * v4.z; aw += wx4 * v4.w;
            ax += wx5 * v5.x; ay += wx5 * v5.y; az += wx5 * v5.z; aw += wx5 * v5.w;
            *(float4*)&rsw[(pwA * 23 + jr) * 4] = make_float4(ax, ay, az, aw);
        }
    }
    asm volatile("s_waitcnt lgkmcnt(0)" ::: "memory");

    // ---- PB: out[bin][c4] = sum_j wy * rs ----
    if (actB) {
        const float* rb = rsw + (pwB * 23 + bjB) * 4;
        const float4 u0 = *(const float4*)(rb +  0);
        const float4 u1 = *(const float4*)(rb +  4);
        const float4 u2 = *(const float4*)(rb +  8);
        const float4 u3 = *(const float4*)(rb + 12);
        const float4 u4 = *(const float4*)(rb + 16);
        const float4 u5 = *(const float4*)(rb + 20);
        float ax = 0.0f, ay = 0.0f, az = 0.0f, aw = 0.0f;
        ax += wy0 * u0.x; ay += wy0 * u0.y; az += wy0 * u0.z; aw += wy0 * u0.w;
        ax += wy1 * u1.x; ay += wy1 * u1.y; az += wy1 * u1.z; aw += wy1 * u1.w;
        ax += wy2 * u2.x; ay += wy2 * u2.y; az += wy2 * u2.z; aw += wy2 * u2.w;
        ax += wy3 * u3.x; ay += wy3 * u3.y; az += wy3 * u3.z; aw += wy3 * u3.w;
        ax += wy4 * u4.x; ay += wy4 * u4.y; az += wy4 * u4.z; aw += wy4 * u4.w;
        ax += wy5 * u5.x; ay += wy5 * u5.y; az += wy5 * u5.z; aw += wy5 * u5.w;
        float* o = out + ((size_t)r * CH + c0) * NBINS + lane;
        o[0 * NBINS] = ax * ia;                 // channel c0
        o[1 * NBINS] = ay * ia;                 // c0+1
        o[2 * NBINS] = az * ia;                 // c0+2
        o[3 * NBINS] = aw * ia;                 // c0+3
    }
}

extern "C" void kernel_launch(void* const* d_in, const int* in_sizes, int n_in,
                              void* d_out, int out_size, void* d_ws, size_t ws_size,
                              hipStream_t stream) {
    const float* feat = (const float*)d_in[0];
    const float* rois = (const float*)d_in[1];
    float* out = (float*)d_out;
    (void)d_ws; (void)ws_size;

    prroi_c4<<<dim3(16, RNUM), 256, 0, stream>>>(feat, rois, out);
}